// Round 6
// baseline (155.163 us; speedup 1.0000x reference)
//
#include <hip/hip_runtime.h>
#include <float.h>

#define B_   2
#define F_   8192
#define Q_   4096
#define NC   128         // F-chunks; 2 per finalize lane
#define FC   (F_/NC)     // 64 triangles per chunk -> 6-bit local index in key
#define PTS  256         // threads per scan block
#define PPT  2           // points per thread in scan (packed fp32)

typedef float f2 __attribute__((ext_vector_type(2)));
typedef unsigned int uint;

__device__ __forceinline__ f2 clamp01(f2 x) {
    f2 z = {0.f, 0.f}, o = {1.f, 1.f};
    return __builtin_elementwise_min(__builtin_elementwise_max(x, z), o);
}

// ---------------------------------------------------------------------------
// Exact reference-order Ericson barycentrics (finalize only). Contract OFF so
// every op rounds exactly like the numpy reference; op order matches the
// reference term-for-term. jnp.select first-true-wins priority; _safe_div.
__device__ __forceinline__ void bary_uvw(
    float ax, float ay, float az,
    float bx, float by, float bz,
    float cx, float cy, float cz,
    float px, float py, float pz,
    float& u, float& v, float& w)
{
#pragma clang fp contract(off)
    float abx = bx - ax, aby = by - ay, abz = bz - az;
    float acx = cx - ax, acy = cy - ay, acz = cz - az;
    float apx = px - ax, apy = py - ay, apz = pz - az;
    float d1 = abx*apx + aby*apy + abz*apz;
    float d2 = acx*apx + acy*apy + acz*apz;
    float bpx = px - bx, bpy = py - by, bpz = pz - bz;
    float d3 = abx*bpx + aby*bpy + abz*bpz;
    float d4 = acx*bpx + acy*bpy + acz*bpz;
    float qx = px - cx, qy = py - cy, qz = pz - cz;
    float d5 = abx*qx + aby*qy + abz*qz;
    float d6 = acx*qx + acy*qy + acz*qz;
    float vc = d1*d4 - d3*d2;
    float vb = d5*d2 - d1*d6;
    float va = d3*d6 - d5*d4;

    bool c1 = (d1 <= 0.f) && (d2 <= 0.f);
    bool c2 = (d3 >= 0.f) && (d4 <= d3);
    bool c3 = (vc <= 0.f) && (d1 >= 0.f) && (d3 <= 0.f);
    bool c4 = (d6 >= 0.f) && (d5 <= d6);
    bool c5 = (vb <= 0.f) && (d2 >= 0.f) && (d6 <= 0.f);
    bool c6 = (va <= 0.f) && (d4 >= d3) && (d5 >= d6);

    bool e1 = c1;
    bool p1 = !c1;
    bool e2 = p1 && c2;
    bool p2 = p1 && !c2;
    bool e3 = p2 && c3;
    bool p3 = p2 && !c3;
    bool e4 = p3 && c4;
    bool p4 = p3 && !c4;
    bool e5 = p4 && c5;
    bool p5 = p4 && !c5;
    bool e6 = p5 && c6;

    float d43 = d4 - d3;
    float d56 = d5 - d6;
    float n  = e3 ? d1        : (e5 ? d2        : (e6 ? d43         : 1.f));
    float dd = e3 ? (d1 - d3) : (e5 ? (d2 - d6) : (e6 ? (d43 + d56) : (va + vb + vc)));
    dd = (dd == 0.f) ? 1.f : dd;   // _safe_div
    float t = n / dd;

    float vi = vb * t;
    float wi = vc * t;
    u = e1 ? 1.f : (e2 ? 0.f : (e3 ? 1.f - t : (e4 ? 0.f : (e5 ? 1.f - t : (e6 ? 0.f     : 1.f - vi - wi)))));
    v = e1 ? 0.f : (e2 ? 1.f : (e3 ? t       : (e4 ? 0.f : (e5 ? 0.f     : (e6 ? 1.f - t : vi)))));
    w = e1 ? 0.f : (e2 ? 0.f : (e3 ? 0.f     : (e4 ? 1.f : (e5 ? t       : (e6 ? t       : wi)))));
}

// ---------------------------------------------------------------------------
// Scan: 2 points/thread packed fp32. Gram-identity inside test (vb==t1,
// vc==t2, denom==|n|^2); top-2 per chunk tracked as sortable uint keys (dist
// bits, low 6 mantissa bits = local face id) -> 3 uint min/max per point per
// triangle. Nomination only; exact re-eval happens in finalize.
__global__ __launch_bounds__(PTS, 8) void scan_kernel(
    const float* __restrict__ tri, const float* __restrict__ pts,
    uint2* __restrict__ keys)
{
    // [0]: ax ay az | daa   [1]: ab | dcc   [2]: ac | dac   [3]: rdaa rdcc rdbc rnn
    __shared__ float4 S[FC * 4];
    const int tid = threadIdx.x;
    const int pb = blockIdx.x, cb = blockIdx.y, bb = blockIdx.z;

    {   // stage: 4 threads per triangle, each writes one float4 of the record
        const int tr = tid & (FC - 1);
        const int qt = tid >> 6;       // 0..3
        const float* g = tri + ((size_t)bb * F_ + (size_t)cb * FC + tr) * 9;
        float ax = g[0], ay = g[1], az = g[2];
        float bx = g[3], by = g[4], bz = g[5];
        float cx = g[6], cy = g[7], cz = g[8];
        float abx = bx - ax, aby = by - ay, abz = bz - az;
        float acx = cx - ax, acy = cy - ay, acz = cz - az;
        float daa = abx*abx + aby*aby + abz*abz;
        float dcc = acx*acx + acy*acy + acz*acz;
        float dac = abx*acx + aby*acy + abz*acz;
        float4 v;
        if (qt == 0)      v = make_float4(ax, ay, az, daa);
        else if (qt == 1) v = make_float4(abx, aby, abz, dcc);
        else if (qt == 2) v = make_float4(acx, acy, acz, dac);
        else {
            float dbc = daa + dcc - 2.f*dac;
            float nn  = daa*dcc - dac*dac;
            v = make_float4(1.f/daa, 1.f/dcc, 1.f/dbc, 1.f/nn);
        }
        S[tr*4 + qt] = v;
    }
    __syncthreads();

    const int q0 = pb * (PTS * PPT) + tid * PPT;
    const float* p0 = pts + ((size_t)bb * Q_ + q0) * 3;
    f2 px = {p0[0], p0[3]};
    f2 py = {p0[1], p0[4]};
    f2 pz = {p0[2], p0[5]};

    uint a0 = 0xFFFFFFFFu, a1 = 0xFFFFFFFFu;   // point0: best / second key
    uint b0 = 0xFFFFFFFFu, b1 = 0xFFFFFFFFu;   // point1
    #pragma unroll 2
    for (int fl = 0; fl < FC; ++fl) {
        float4 c0 = S[fl*4 + 0];
        float4 c1 = S[fl*4 + 1];
        float4 c2 = S[fl*4 + 2];
        float4 c3 = S[fl*4 + 3];
        float daa = c0.w, dcc = c1.w, dac = c2.w;
        float dbc = daa + dcc - 2.f*dac;
        float nn  = daa*dcc - dac*dac;
        float kk  = daa - dac;

        f2 apx = px - c0.x, apy = py - c0.y, apz = pz - c0.z;
        f2 d1  = c1.x*apx + c1.y*apy + c1.z*apz;
        f2 d2  = c2.x*apx + c2.y*apy + c2.z*apz;
        f2 app = apx*apx + apy*apy + apz*apz;
        f2 t1  = d1*dcc - d2*dac;               // == vb (Gram)
        f2 t2  = d2*daa - d1*dac;               // == vc
        f2 t12 = t1 + t2;
        f2 sg  = d1*t1 + d2*t2;
        f2 dint = app - sg*c3.w;                // plane dist^2

        f2 d43 = (d2 - d1) + kk;                // d4 - d3
        f2 td1 = d1 + d1;
        f2 tab = clamp01(d1 * c3.x);
        f2 eab = app - tab*(td1 - tab*daa);
        f2 tac = clamp01(d2 * c3.y);
        f2 eac = app - tac*((d2 + d2) - tac*dcc);
        f2 bpp = (app - td1) + daa;
        f2 sbc = clamp01(d43 * c3.z);
        f2 ebc = bpp - sbc*((d43 + d43) - sbc*dbc);
        f2 emin = __builtin_elementwise_min(__builtin_elementwise_min(eab, eac), ebc);

        bool inA = (t1.x >= 0.f) & (t2.x >= 0.f) & (t12.x <= nn);
        bool inB = (t1.y >= 0.f) & (t2.y >= 0.f) & (t12.y <= nn);
        float dA = fmaxf(inA ? dint.x : emin.x, 0.f);   // clamp: neg would wrap key
        float dB = fmaxf(inB ? dint.y : emin.y, 0.f);

        // sortable key: nonneg-float bits are order-isomorphic to uint;
        // low 6 mantissa bits carry the local face id (nomination only).
        uint kA = (__float_as_uint(dA) & 0xFFFFFFC0u) | (uint)fl;
        uint kB = (__float_as_uint(dB) & 0xFFFFFFC0u) | (uint)fl;
        uint lo = min(a0, kA), hi = max(a0, kA);
        a0 = lo; a1 = min(a1, hi);
        lo = min(b0, kB); hi = max(b0, kB);
        b0 = lo; b1 = min(b1, hi);
    }

    size_t o = ((size_t)bb * Q_ + q0) * NC + cb;
    keys[o]      = make_uint2(a0, a1);
    keys[o + NC] = make_uint2(b0, b1);
}

// ---------------------------------------------------------------------------
// Finalize: one WAVE per point; lane l holds chunks 2l,2l+1 (4 candidate keys,
// coalesced uint4 load). ALL 4 candidates exactly evaluated with the np-order
// formula (contract off -> bitwise-identical d^2); lex-(d, face) reduce ==
// jnp.argmin first occurrence. NO cheap-distance filtering: the cheap formula
// has an unbounded error tail on sliver triangles (1/sin^2 amplification),
// so any finite window can drop the true winner (R5 failure). Lane 0 epilogue.
__global__ __launch_bounds__(256) void finalize_kernel(
    const float* __restrict__ tri, const float* __restrict__ pts,
    const float* __restrict__ nrm, const float* __restrict__ cmp,
    const int* __restrict__ faces,
    const uint* __restrict__ keys,
    float* __restrict__ out)
{
#pragma clang fp contract(off)
    const int lane = threadIdx.x & 63;
    const int t = blockIdx.x * 4 + (threadIdx.x >> 6);
    const int bb = t / Q_;

    const float* pp = pts + (size_t)t * 3;
    float px = pp[0], py = pp[1], pz = pp[2];

    const uint4* kp = (const uint4*)keys;
    uint4 K = kp[(size_t)t * (NC/2) + lane];   // chunk 2l: (x,y); chunk 2l+1: (z,w)

    float dbest = FLT_MAX; int fbest = 0x7FFFFFFF;
    uint kj[4] = {K.x, K.y, K.z, K.w};
    #pragma unroll
    for (int j = 0; j < 4; ++j) {
        int face = (2*lane + (j >> 1)) * FC + (int)(kj[j] & 63u);
        const float* tg = tri + ((size_t)bb * F_ + face) * 9;
        float ax = tg[0], ay = tg[1], az = tg[2];
        float bx = tg[3], by = tg[4], bz = tg[5];
        float cx = tg[6], cy = tg[7], cz = tg[8];
        float u, v, w;
        bary_uvw(ax, ay, az, bx, by, bz, cx, cy, cz, px, py, pz, u, v, w);
        float cpx = u*ax + v*bx + w*cx;
        float cpy = u*ay + v*by + w*cy;
        float cpz = u*az + v*bz + w*cz;
        float dx = cpx - px, dy = cpy - py, dz = cpz - pz;
        float d2v = dx*dx + dy*dy + dz*dz;
        if (d2v < dbest || (d2v == dbest && face < fbest)) { dbest = d2v; fbest = face; }
    }
    for (int off = 32; off > 0; off >>= 1) {
        float od = __shfl_down(dbest, off);
        int   of = __shfl_down(fbest, off);
        if (od < dbest || (od == dbest && of < fbest)) { dbest = od; fbest = of; }
    }
    fbest = __shfl(fbest, 0);
    if (lane != 0) return;

    const int bestf = fbest;
    const float* tg = tri + ((size_t)bb * F_ + bestf) * 9;
    const float* ng = nrm + ((size_t)bb * F_ + bestf) * 9;
    const float* cg = cmp + ((size_t)bb * F_ + bestf) * 9;

    float u, v, w;
    bary_uvw(tg[0], tg[1], tg[2],  tg[3], tg[4], tg[5],  tg[6], tg[7], tg[8],
             px, py, pz, u, v, w);
    u = fminf(fmaxf(u, 0.f), 1.f);
    v = fminf(fmaxf(v, 0.f), 1.f);
    w = fminf(fmaxf(w, 0.f), 1.f);

    float cpx = u * tg[0] + v * tg[3] + w * tg[6];
    float cpy = u * tg[1] + v * tg[4] + w * tg[7];
    float cpz = u * tg[2] + v * tg[5] + w * tg[8];
    float nx  = u * ng[0] + v * ng[3] + w * ng[6];
    float ny  = u * ng[1] + v * ng[4] + w * ng[7];
    float nz  = u * ng[2] + v * ng[5] + w * ng[8];
    float mx  = u * cg[0] + v * cg[3] + w * cg[6];
    float my  = u * cg[1] + v * cg[4] + w * cg[7];
    float mz  = u * cg[2] + v * cg[5] + w * cg[8];

    const size_t S3 = (size_t)B_ * Q_ * 3;
    out[(size_t)t * 3 + 0] = cpx - px;
    out[(size_t)t * 3 + 1] = cpy - py;
    out[(size_t)t * 3 + 2] = cpz - pz;
    out[S3 + (size_t)t * 3 + 0] = nx;
    out[S3 + (size_t)t * 3 + 1] = ny;
    out[S3 + (size_t)t * 3 + 2] = nz;
    out[2 * S3 + (size_t)t * 3 + 0] = mx;
    out[2 * S3 + (size_t)t * 3 + 1] = my;
    out[2 * S3 + (size_t)t * 3 + 2] = mz;

    int k = 0; float mm = u;
    if (v > mm) { mm = v; k = 1; }
    if (w > mm) { k = 2; }
    out[3 * S3 + t] = (float)faces[((size_t)bb * F_ + bestf) * 3 + k];
}

extern "C" void kernel_launch(void* const* d_in, const int* in_sizes, int n_in,
                              void* d_out, int out_size, void* d_ws, size_t ws_size,
                              hipStream_t stream) {
    const float* tri   = (const float*)d_in[0];
    const float* pts   = (const float*)d_in[1];
    const float* nrm   = (const float*)d_in[2];
    const float* cmp   = (const float*)d_in[3];
    const int*   faces = (const int*)d_in[4];
    float* out = (float*)d_out;

    uint2* keys = (uint2*)d_ws;   // [B*Q*NC] top-2 keys; fully written by scan

    dim3 g1(Q_ / (PTS * PPT), NC, B_);
    scan_kernel<<<g1, PTS, 0, stream>>>(tri, pts, keys);
    finalize_kernel<<<(B_ * Q_) / 4, 256, 0, stream>>>(
        tri, pts, nrm, cmp, faces, (const uint*)keys, out);
}

// Round 7
// 148.147 us; speedup vs baseline: 1.0474x; 1.0474x over previous
//
#include <hip/hip_runtime.h>
#include <float.h>

#define B_   2
#define F_   8192
#define Q_   4096
#define NC   128         // F-chunks; 2 per finalize lane
#define FC   (F_/NC)     // 64 triangles per chunk -> 6-bit local index in key
#define PTS  128         // threads per scan block
#define PPT  4           // points per thread in scan (2 packed fp32 pairs)

typedef float f2 __attribute__((ext_vector_type(2)));
typedef float f4u __attribute__((ext_vector_type(4), aligned(4)));  // 4B-aligned float4 load
typedef unsigned int uint;

__device__ __forceinline__ f2 clamp01(f2 x) {
    f2 z = {0.f, 0.f}, o = {1.f, 1.f};
    return __builtin_elementwise_min(__builtin_elementwise_max(x, z), o);
}

// ---------------------------------------------------------------------------
// Exact reference-order Ericson barycentrics (finalize only). Contract OFF so
// every op rounds exactly like the numpy reference; op order matches the
// reference term-for-term. jnp.select first-true-wins priority; _safe_div.
__device__ __forceinline__ void bary_uvw(
    float ax, float ay, float az,
    float bx, float by, float bz,
    float cx, float cy, float cz,
    float px, float py, float pz,
    float& u, float& v, float& w)
{
#pragma clang fp contract(off)
    float abx = bx - ax, aby = by - ay, abz = bz - az;
    float acx = cx - ax, acy = cy - ay, acz = cz - az;
    float apx = px - ax, apy = py - ay, apz = pz - az;
    float d1 = abx*apx + aby*apy + abz*apz;
    float d2 = acx*apx + acy*apy + acz*apz;
    float bpx = px - bx, bpy = py - by, bpz = pz - bz;
    float d3 = abx*bpx + aby*bpy + abz*bpz;
    float d4 = acx*bpx + acy*bpy + acz*bpz;
    float qx = px - cx, qy = py - cy, qz = pz - cz;
    float d5 = abx*qx + aby*qy + abz*qz;
    float d6 = acx*qx + acy*qy + acz*qz;
    float vc = d1*d4 - d3*d2;
    float vb = d5*d2 - d1*d6;
    float va = d3*d6 - d5*d4;

    bool c1 = (d1 <= 0.f) && (d2 <= 0.f);
    bool c2 = (d3 >= 0.f) && (d4 <= d3);
    bool c3 = (vc <= 0.f) && (d1 >= 0.f) && (d3 <= 0.f);
    bool c4 = (d6 >= 0.f) && (d5 <= d6);
    bool c5 = (vb <= 0.f) && (d2 >= 0.f) && (d6 <= 0.f);
    bool c6 = (va <= 0.f) && (d4 >= d3) && (d5 >= d6);

    bool e1 = c1;
    bool p1 = !c1;
    bool e2 = p1 && c2;
    bool p2 = p1 && !c2;
    bool e3 = p2 && c3;
    bool p3 = p2 && !c3;
    bool e4 = p3 && c4;
    bool p4 = p3 && !c4;
    bool e5 = p4 && c5;
    bool p5 = p4 && !c5;
    bool e6 = p5 && c6;

    float d43 = d4 - d3;
    float d56 = d5 - d6;
    float n  = e3 ? d1        : (e5 ? d2        : (e6 ? d43         : 1.f));
    float dd = e3 ? (d1 - d3) : (e5 ? (d2 - d6) : (e6 ? (d43 + d56) : (va + vb + vc)));
    dd = (dd == 0.f) ? 1.f : dd;   // _safe_div
    float t = n / dd;

    float vi = vb * t;
    float wi = vc * t;
    u = e1 ? 1.f : (e2 ? 0.f : (e3 ? 1.f - t : (e4 ? 0.f : (e5 ? 1.f - t : (e6 ? 0.f     : 1.f - vi - wi)))));
    v = e1 ? 0.f : (e2 ? 1.f : (e3 ? t       : (e4 ? 0.f : (e5 ? 0.f     : (e6 ? 1.f - t : vi)))));
    w = e1 ? 0.f : (e2 ? 0.f : (e3 ? 0.f     : (e4 ? 1.f : (e5 ? t       : (e6 ? t       : wi)))));
}

// ---------------------------------------------------------------------------
// Cheap distance^2 for one pair of points vs one triangle, "app - max(red)"
// form. Nomination-only; exact re-eval happens in finalize.
__device__ __forceinline__ f2 pair_dist(
    f2 px, f2 py, f2 pz,
    float ax, float ay, float az,
    float abx, float aby, float abz,
    float acx, float acy, float acz,
    float daa, float dcc, float dac, float dbc, float kk,
    float rdaa, float rdcc, float rdbc, float rnn)
{
    f2 apx = px - ax, apy = py - ay, apz = pz - az;
    f2 d1  = abx*apx + aby*apy + abz*apz;
    f2 d2  = acx*apx + acy*apy + acz*apz;
    f2 app = apx*apx + apy*apy + apz*apz;

    f2 t1 = d1*dcc - d2*dac;                  // Gram solve numerators
    f2 t2 = d2*daa - d1*dac;
    f2 t12n = 1.f - (t1 + t2)*rnn;            // >=0  <=>  t1+t2 <= nn
    f2 sgr  = (d1*t1 + d2*t2)*rnn;            // interior reduction
    f2 ins  = __builtin_elementwise_min(__builtin_elementwise_min(t1, t2), t12n);

    f2 td1 = d1 + d1;
    f2 tab = clamp01(d1 * rdaa);
    f2 rab = tab*(td1 - tab*daa);             // edge AB reduction
    f2 tac = clamp01(d2 * rdcc);
    f2 rac = tac*((d2 + d2) - tac*dcc);       // edge AC
    f2 d43 = (d2 - d1) + kk;                  // d4 - d3
    f2 sbc = clamp01(d43 * rdbc);
    f2 rbc = (td1 - daa) + sbc*((d43 + d43) - sbc*dbc);  // edge BC (vs app)
    f2 rmax = __builtin_elementwise_max(__builtin_elementwise_max(rab, rac), rbc);

    f2 red;
    red.x = (ins.x >= 0.f) ? sgr.x : rmax.x;
    red.y = (ins.y >= 0.f) ? sgr.y : rmax.y;
    f2 z = {0.f, 0.f};
    return __builtin_elementwise_max(app - red, z);   // clamp: neg would wrap key
}

// ---------------------------------------------------------------------------
// Scan: 4 points/thread (2 packed pairs) amortize per-triangle LDS reads and
// derivations over 256 tests/wave-iter. Top-2 per chunk as sortable uint keys
// (dist bits | 6-bit local face id). Keys stored CHUNK-MAJOR [b][chunk][q]
// so stores are fully coalesced (2x dwordx4 per thread).
__global__ __launch_bounds__(PTS, 4) void scan_kernel(
    const float* __restrict__ tri, const float* __restrict__ pts,
    uint2* __restrict__ keys)
{
    // [0]: ax ay az | daa   [1]: ab | dcc   [2]: ac | dac   [3]: rdaa rdcc rdbc rnn
    __shared__ float4 S[FC * 4];
    const int tid = threadIdx.x;
    const int pb = blockIdx.x, cb = blockIdx.y, bb = blockIdx.z;

    {   // stage: 128 threads, 64 tris; each thread writes records hf and hf+2
        const int tr = tid & (FC - 1);
        const int hf = tid >> 6;       // 0 or 1
        const float* g = tri + ((size_t)bb * F_ + (size_t)cb * FC + tr) * 9;
        float ax = g[0], ay = g[1], az = g[2];
        float bx = g[3], by = g[4], bz = g[5];
        float cx = g[6], cy = g[7], cz = g[8];
        float abx = bx - ax, aby = by - ay, abz = bz - az;
        float acx = cx - ax, acy = cy - ay, acz = cz - az;
        float daa = abx*abx + aby*aby + abz*abz;
        float dcc = acx*acx + acy*acy + acz*acz;
        float dac = abx*acx + aby*acy + abz*acz;
        if (hf == 0) {
            S[tr*4 + 0] = make_float4(ax, ay, az, daa);
            S[tr*4 + 2] = make_float4(acx, acy, acz, dac);
        } else {
            float dbc = daa + dcc - 2.f*dac;
            float nn  = daa*dcc - dac*dac;
            S[tr*4 + 1] = make_float4(abx, aby, abz, dcc);
            S[tr*4 + 3] = make_float4(1.f/daa, 1.f/dcc, 1.f/dbc, 1.f/nn);
        }
    }
    __syncthreads();

    const int q0 = pb * (PTS * PPT) + tid * PPT;   // 4 consecutive points
    const float* p0 = pts + ((size_t)bb * Q_ + q0) * 3;
    f4u l0 = *(const f4u*)(p0);
    f4u l1 = *(const f4u*)(p0 + 4);
    f4u l2 = *(const f4u*)(p0 + 8);
    f2 pxA = {l0.x, l0.w}, pyA = {l0.y, l1.x}, pzA = {l0.z, l1.y};
    f2 pxB = {l1.z, l2.y}, pyB = {l1.w, l2.z}, pzB = {l2.x, l2.w};

    uint k00 = 0xFFFFFFFFu, k01 = 0xFFFFFFFFu;   // point0 best/second
    uint k10 = 0xFFFFFFFFu, k11 = 0xFFFFFFFFu;
    uint k20 = 0xFFFFFFFFu, k21 = 0xFFFFFFFFu;
    uint k30 = 0xFFFFFFFFu, k31 = 0xFFFFFFFFu;
    #pragma unroll 2
    for (int fl = 0; fl < FC; ++fl) {
        float4 c0 = S[fl*4 + 0];
        float4 c1 = S[fl*4 + 1];
        float4 c2 = S[fl*4 + 2];
        float4 c3 = S[fl*4 + 3];
        float daa = c0.w, dcc = c1.w, dac = c2.w;
        float dbc = daa + dcc - 2.f*dac;
        float kk  = daa - dac;

        f2 dA = pair_dist(pxA, pyA, pzA, c0.x, c0.y, c0.z,
                          c1.x, c1.y, c1.z, c2.x, c2.y, c2.z,
                          daa, dcc, dac, dbc, kk, c3.x, c3.y, c3.z, c3.w);
        f2 dB = pair_dist(pxB, pyB, pzB, c0.x, c0.y, c0.z,
                          c1.x, c1.y, c1.z, c2.x, c2.y, c2.z,
                          daa, dcc, dac, dbc, kk, c3.x, c3.y, c3.z, c3.w);

        uint kA0 = (__float_as_uint(dA.x) & 0xFFFFFFC0u) | (uint)fl;
        uint kA1 = (__float_as_uint(dA.y) & 0xFFFFFFC0u) | (uint)fl;
        uint kB0 = (__float_as_uint(dB.x) & 0xFFFFFFC0u) | (uint)fl;
        uint kB1 = (__float_as_uint(dB.y) & 0xFFFFFFC0u) | (uint)fl;
        uint lo, hi;
        lo = min(k00, kA0); hi = max(k00, kA0); k00 = lo; k01 = min(k01, hi);
        lo = min(k10, kA1); hi = max(k10, kA1); k10 = lo; k11 = min(k11, hi);
        lo = min(k20, kB0); hi = max(k20, kB0); k20 = lo; k21 = min(k21, hi);
        lo = min(k30, kB1); hi = max(k30, kB1); k30 = lo; k31 = min(k31, hi);
    }

    // chunk-major [b][chunk][q]: coalesced dwordx4 stores (q0 even -> 16B aligned)
    size_t idx = ((size_t)(bb * NC + cb) * Q_ + q0);
    uint4* k4 = (uint4*)&keys[idx];
    k4[0] = make_uint4(k00, k01, k10, k11);
    k4[1] = make_uint4(k20, k21, k30, k31);
}

// ---------------------------------------------------------------------------
// Finalize: one WAVE per point; lane l holds chunks 2l,2l+1 (4 candidates).
// ALL 4 exactly evaluated with the np-order formula (contract off); triangle
// gathers as 2x dwordx4 + 1 dword batched up-front (divergent-VMEM count
// 37 -> ~14 per lane). lex-(d, face) reduce == jnp.argmin first occurrence.
// NO cheap-distance filtering (R5 lesson: unbounded sliver error tail).
__global__ __launch_bounds__(256) void finalize_kernel(
    const float* __restrict__ tri, const float* __restrict__ pts,
    const float* __restrict__ nrm, const float* __restrict__ cmp,
    const int* __restrict__ faces,
    const uint2* __restrict__ keys,
    float* __restrict__ out)
{
#pragma clang fp contract(off)
    const int lane = threadIdx.x & 63;
    const int t = blockIdx.x * 4 + (threadIdx.x >> 6);
    const int bb = t >> 12;            // Q_ = 4096
    const int q  = t & (Q_ - 1);

    const float* pp = pts + (size_t)t * 3;
    float px = pp[0], py = pp[1], pz = pp[2];

    uint2 kc0 = keys[((size_t)(bb * NC + 2*lane    ) * Q_ + q)];
    uint2 kc1 = keys[((size_t)(bb * NC + 2*lane + 1) * Q_ + q)];

    int face[4];
    face[0] = (2*lane    ) * FC + (int)(kc0.x & 63u);
    face[1] = (2*lane    ) * FC + (int)(kc0.y & 63u);
    face[2] = (2*lane + 1) * FC + (int)(kc1.x & 63u);
    face[3] = (2*lane + 1) * FC + (int)(kc1.y & 63u);

    // batched gathers: 4 tris x (2x dwordx4 + 1 dword)
    f4u A[4], Bv[4]; float Cs[4];
    #pragma unroll
    for (int j = 0; j < 4; ++j) {
        const float* tg = tri + ((size_t)bb * F_ + face[j]) * 9;
        A[j]  = *(const f4u*)(tg);
        Bv[j] = *(const f4u*)(tg + 4);
        Cs[j] = tg[8];
    }

    float dbest = FLT_MAX; int fbest = 0x7FFFFFFF;
    #pragma unroll
    for (int j = 0; j < 4; ++j) {
        float ax = A[j].x, ay = A[j].y, az = A[j].z;
        float bx = A[j].w, by = Bv[j].x, bz = Bv[j].y;
        float cx = Bv[j].z, cy = Bv[j].w, cz = Cs[j];
        float u, v, w;
        bary_uvw(ax, ay, az, bx, by, bz, cx, cy, cz, px, py, pz, u, v, w);
        float cpx = u*ax + v*bx + w*cx;
        float cpy = u*ay + v*by + w*cy;
        float cpz = u*az + v*bz + w*cz;
        float dx = cpx - px, dy = cpy - py, dz = cpz - pz;
        float d2v = dx*dx + dy*dy + dz*dz;
        int fj = face[j];
        if (d2v < dbest || (d2v == dbest && fj < fbest)) { dbest = d2v; fbest = fj; }
    }
    for (int off = 32; off > 0; off >>= 1) {
        float od = __shfl_down(dbest, off);
        int   of = __shfl_down(fbest, off);
        if (od < dbest || (od == dbest && of < fbest)) { dbest = od; fbest = of; }
    }
    fbest = __shfl(fbest, 0);
    if (lane != 0) return;

    const int bestf = fbest;
    const float* tg = tri + ((size_t)bb * F_ + bestf) * 9;
    const float* ng = nrm + ((size_t)bb * F_ + bestf) * 9;
    const float* cg = cmp + ((size_t)bb * F_ + bestf) * 9;
    f4u TA = *(const f4u*)(tg), TB = *(const f4u*)(tg + 4);
    float TC = tg[8];
    f4u NA = *(const f4u*)(ng), NB = *(const f4u*)(ng + 4);
    float NCs = ng[8];
    f4u CA = *(const f4u*)(cg), CB = *(const f4u*)(cg + 4);
    float CC = cg[8];

    float u, v, w;
    bary_uvw(TA.x, TA.y, TA.z, TA.w, TB.x, TB.y, TB.z, TB.w, TC,
             px, py, pz, u, v, w);
    u = fminf(fmaxf(u, 0.f), 1.f);
    v = fminf(fmaxf(v, 0.f), 1.f);
    w = fminf(fmaxf(w, 0.f), 1.f);

    float cpx = u * TA.x + v * TA.w + w * TB.z;
    float cpy = u * TA.y + v * TB.x + w * TB.w;
    float cpz = u * TA.z + v * TB.y + w * TC;
    float nx  = u * NA.x + v * NA.w + w * NB.z;
    float ny  = u * NA.y + v * NB.x + w * NB.w;
    float nz  = u * NA.z + v * NB.y + w * NCs;
    float mx  = u * CA.x + v * CA.w + w * CB.z;
    float my  = u * CA.y + v * CB.x + w * CB.w;
    float mz  = u * CA.z + v * CB.y + w * CC;

    const size_t S3 = (size_t)B_ * Q_ * 3;
    out[(size_t)t * 3 + 0] = cpx - px;
    out[(size_t)t * 3 + 1] = cpy - py;
    out[(size_t)t * 3 + 2] = cpz - pz;
    out[S3 + (size_t)t * 3 + 0] = nx;
    out[S3 + (size_t)t * 3 + 1] = ny;
    out[S3 + (size_t)t * 3 + 2] = nz;
    out[2 * S3 + (size_t)t * 3 + 0] = mx;
    out[2 * S3 + (size_t)t * 3 + 1] = my;
    out[2 * S3 + (size_t)t * 3 + 2] = mz;

    int k = 0; float mm = u;
    if (v > mm) { mm = v; k = 1; }
    if (w > mm) { k = 2; }
    out[3 * S3 + t] = (float)faces[((size_t)bb * F_ + bestf) * 3 + k];
}

extern "C" void kernel_launch(void* const* d_in, const int* in_sizes, int n_in,
                              void* d_out, int out_size, void* d_ws, size_t ws_size,
                              hipStream_t stream) {
    const float* tri   = (const float*)d_in[0];
    const float* pts   = (const float*)d_in[1];
    const float* nrm   = (const float*)d_in[2];
    const float* cmp   = (const float*)d_in[3];
    const int*   faces = (const int*)d_in[4];
    float* out = (float*)d_out;

    uint2* keys = (uint2*)d_ws;   // [B][NC][Q] top-2 keys, chunk-major

    dim3 g1(Q_ / (PTS * PPT), NC, B_);
    scan_kernel<<<g1, PTS, 0, stream>>>(tri, pts, keys);
    finalize_kernel<<<(B_ * Q_) / 4, 256, 0, stream>>>(
        tri, pts, nrm, cmp, faces, keys, out);
}

// Round 9
// 140.842 us; speedup vs baseline: 1.1017x; 1.0519x over previous
//
#include <hip/hip_runtime.h>
#include <float.h>

#define B_   2
#define F_   8192
#define Q_   4096
#define NC   128         // F-chunks; 2 exact pairs per finalize lane
#define FC   (F_/NC)     // 64 triangles per chunk -> 6-bit local index in key
#define PTS  256         // threads per scan block
#define PPT  4           // points per thread in scan (2 packed fp32 pairs)

typedef float f2 __attribute__((ext_vector_type(2)));
typedef float f4u __attribute__((ext_vector_type(4), aligned(4)));
typedef unsigned int uint;

__device__ __forceinline__ f2 clamp01(f2 x) {
    f2 z = {0.f, 0.f}, o = {1.f, 1.f};
    return __builtin_elementwise_min(__builtin_elementwise_max(x, z), o);
}

// ---------------------------------------------------------------------------
// Exact reference-order Ericson barycentrics. Contract OFF: every op rounds
// exactly like the numpy reference; op order matches term-for-term.
// jnp.select first-true-wins priority; _safe_div(n,d) = n/(d==0?1:d).
__device__ __forceinline__ void bary_uvw(
    float ax, float ay, float az,
    float bx, float by, float bz,
    float cx, float cy, float cz,
    float px, float py, float pz,
    float& u, float& v, float& w)
{
#pragma clang fp contract(off)
    float abx = bx - ax, aby = by - ay, abz = bz - az;
    float acx = cx - ax, acy = cy - ay, acz = cz - az;
    float apx = px - ax, apy = py - ay, apz = pz - az;
    float d1 = abx*apx + aby*apy + abz*apz;
    float d2 = acx*apx + acy*apy + acz*apz;
    float bpx = px - bx, bpy = py - by, bpz = pz - bz;
    float d3 = abx*bpx + aby*bpy + abz*bpz;
    float d4 = acx*bpx + acy*bpy + acz*bpz;
    float qx = px - cx, qy = py - cy, qz = pz - cz;
    float d5 = abx*qx + aby*qy + abz*qz;
    float d6 = acx*qx + acy*qy + acz*qz;
    float vc = d1*d4 - d3*d2;
    float vb = d5*d2 - d1*d6;
    float va = d3*d6 - d5*d4;

    bool c1 = (d1 <= 0.f) && (d2 <= 0.f);
    bool c2 = (d3 >= 0.f) && (d4 <= d3);
    bool c3 = (vc <= 0.f) && (d1 >= 0.f) && (d3 <= 0.f);
    bool c4 = (d6 >= 0.f) && (d5 <= d6);
    bool c5 = (vb <= 0.f) && (d2 >= 0.f) && (d6 <= 0.f);
    bool c6 = (va <= 0.f) && (d4 >= d3) && (d5 >= d6);

    bool e1 = c1;
    bool p1 = !c1;
    bool e2 = p1 && c2;
    bool p2 = p1 && !c2;
    bool e3 = p2 && c3;
    bool p3 = p2 && !c3;
    bool e4 = p3 && c4;
    bool p4 = p3 && !c4;
    bool e5 = p4 && c5;
    bool p5 = p4 && !c5;
    bool e6 = p5 && c6;

    float d43 = d4 - d3;
    float d56 = d5 - d6;
    float n  = e3 ? d1        : (e5 ? d2        : (e6 ? d43         : 1.f));
    float dd = e3 ? (d1 - d3) : (e5 ? (d2 - d6) : (e6 ? (d43 + d56) : (va + vb + vc)));
    dd = (dd == 0.f) ? 1.f : dd;   // _safe_div
    float t = n / dd;

    float vi = vb * t;
    float wi = vc * t;
    u = e1 ? 1.f : (e2 ? 0.f : (e3 ? 1.f - t : (e4 ? 0.f : (e5 ? 1.f - t : (e6 ? 0.f     : 1.f - vi - wi)))));
    v = e1 ? 0.f : (e2 ? 1.f : (e3 ? t       : (e4 ? 0.f : (e5 ? 0.f     : (e6 ? 1.f - t : vi)))));
    w = e1 ? 0.f : (e2 ? 0.f : (e3 ? 0.f     : (e4 ? 1.f : (e5 ? t       : (e6 ? t       : wi)))));
}

// Cheap nomination distance^2, one point-pair vs one triangle.
__device__ __forceinline__ f2 pair_dist(
    f2 px, f2 py, f2 pz,
    float ax, float ay, float az,
    float abx, float aby, float abz,
    float acx, float acy, float acz,
    float daa, float dcc, float dac, float dbc, float kk,
    float rdaa, float rdcc, float rdbc, float rnn)
{
    f2 apx = px - ax, apy = py - ay, apz = pz - az;
    f2 d1  = abx*apx + aby*apy + abz*apz;
    f2 d2  = acx*apx + acy*apy + acz*apz;
    f2 app = apx*apx + apy*apy + apz*apz;

    f2 t1 = d1*dcc - d2*dac;
    f2 t2 = d2*daa - d1*dac;
    f2 t12n = 1.f - (t1 + t2)*rnn;
    f2 sgr  = (d1*t1 + d2*t2)*rnn;
    f2 ins  = __builtin_elementwise_min(__builtin_elementwise_min(t1, t2), t12n);

    f2 td1 = d1 + d1;
    f2 tab = clamp01(d1 * rdaa);
    f2 rab = tab*(td1 - tab*daa);
    f2 tac = clamp01(d2 * rdcc);
    f2 rac = tac*((d2 + d2) - tac*dcc);
    f2 d43 = (d2 - d1) + kk;
    f2 sbc = clamp01(d43 * rdbc);
    f2 rbc = (td1 - daa) + sbc*((d43 + d43) - sbc*dbc);
    f2 rmax = __builtin_elementwise_max(__builtin_elementwise_max(rab, rac), rbc);

    f2 red;
    red.x = (ins.x >= 0.f) ? sgr.x : rmax.x;
    red.y = (ins.y >= 0.f) ? sgr.y : rmax.y;
    f2 z = {0.f, 0.f};
    return __builtin_elementwise_max(app - red, z);   // clamp: neg would wrap key
}

// ---------------------------------------------------------------------------
// Scan: cheap loop nominates top-2/chunk (sortable uint keys); TAIL exact-
// evaluates both nominees per point with the np-order contract-off formula
// reading RAW a,b,c from LDS (bit-identical inputs => bit-identical d^2) and
// emits one (d_exact_bits, face) pair per (point, chunk). Finalize needs no
// candidate gathers. NO cheap-distance filtering anywhere (R5 lesson).
__global__ __launch_bounds__(PTS, 4) void scan_kernel(
    const float* __restrict__ tri, const float* __restrict__ pts,
    uint2* __restrict__ keys)
{
    // per-tri 6 x float4: [0] a|daa  [1] ab|dcc  [2] ac|dac  [3] recips  [4] b  [5] c
    __shared__ float4 S[FC * 6];
    const int tid = threadIdx.x;
    const int pb = blockIdx.x, cb = blockIdx.y, bb = blockIdx.z;

    if (tid < FC) {   // one thread stages one triangle fully
        const float* g = tri + ((size_t)bb * F_ + (size_t)cb * FC + tid) * 9;
        float ax = g[0], ay = g[1], az = g[2];
        float bx = g[3], by = g[4], bz = g[5];
        float cx = g[6], cy = g[7], cz = g[8];
        float abx = bx - ax, aby = by - ay, abz = bz - az;
        float acx = cx - ax, acy = cy - ay, acz = cz - az;
        float daa = abx*abx + aby*aby + abz*abz;
        float dcc = acx*acx + acy*acy + acz*acz;
        float dac = abx*acx + aby*acy + abz*acz;
        float dbc = daa + dcc - 2.f*dac;
        float nn  = daa*dcc - dac*dac;
        S[tid*6 + 0] = make_float4(ax, ay, az, daa);
        S[tid*6 + 1] = make_float4(abx, aby, abz, dcc);
        S[tid*6 + 2] = make_float4(acx, acy, acz, dac);
        S[tid*6 + 3] = make_float4(1.f/daa, 1.f/dcc, 1.f/dbc, 1.f/nn);
        S[tid*6 + 4] = make_float4(bx, by, bz, 0.f);
        S[tid*6 + 5] = make_float4(cx, cy, cz, 0.f);
    }
    __syncthreads();

    const int q0 = pb * (PTS * PPT) + tid * PPT;
    const float* p0 = pts + ((size_t)bb * Q_ + q0) * 3;
    f4u l0 = *(const f4u*)(p0);
    f4u l1 = *(const f4u*)(p0 + 4);
    f4u l2 = *(const f4u*)(p0 + 8);
    f2 pxA = {l0.x, l0.w}, pyA = {l0.y, l1.x}, pzA = {l0.z, l1.y};
    f2 pxB = {l1.z, l2.y}, pyB = {l1.w, l2.z}, pzB = {l2.x, l2.w};

    uint k00 = 0xFFFFFFFFu, k01 = 0xFFFFFFFFu;
    uint k10 = 0xFFFFFFFFu, k11 = 0xFFFFFFFFu;
    uint k20 = 0xFFFFFFFFu, k21 = 0xFFFFFFFFu;
    uint k30 = 0xFFFFFFFFu, k31 = 0xFFFFFFFFu;
    #pragma unroll 2
    for (int fl = 0; fl < FC; ++fl) {
        float4 c0 = S[fl*6 + 0];
        float4 c1 = S[fl*6 + 1];
        float4 c2 = S[fl*6 + 2];
        float4 c3 = S[fl*6 + 3];
        float daa = c0.w, dcc = c1.w, dac = c2.w;
        float dbc = daa + dcc - 2.f*dac;
        float kk  = daa - dac;

        f2 dA = pair_dist(pxA, pyA, pzA, c0.x, c0.y, c0.z,
                          c1.x, c1.y, c1.z, c2.x, c2.y, c2.z,
                          daa, dcc, dac, dbc, kk, c3.x, c3.y, c3.z, c3.w);
        f2 dB = pair_dist(pxB, pyB, pzB, c0.x, c0.y, c0.z,
                          c1.x, c1.y, c1.z, c2.x, c2.y, c2.z,
                          daa, dcc, dac, dbc, kk, c3.x, c3.y, c3.z, c3.w);

        uint kA0 = (__float_as_uint(dA.x) & 0xFFFFFFC0u) | (uint)fl;
        uint kA1 = (__float_as_uint(dA.y) & 0xFFFFFFC0u) | (uint)fl;
        uint kB0 = (__float_as_uint(dB.x) & 0xFFFFFFC0u) | (uint)fl;
        uint kB1 = (__float_as_uint(dB.y) & 0xFFFFFFC0u) | (uint)fl;
        uint lo, hi;
        lo = min(k00, kA0); hi = max(k00, kA0); k00 = lo; k01 = min(k01, hi);
        lo = min(k10, kA1); hi = max(k10, kA1); k10 = lo; k11 = min(k11, hi);
        lo = min(k20, kB0); hi = max(k20, kB0); k20 = lo; k21 = min(k21, hi);
        lo = min(k30, kB1); hi = max(k30, kB1); k30 = lo; k31 = min(k31, hi);
    }

    // TAIL: exact np-order eval of both nominees per point (raw coords from LDS)
    float pxs[4] = {l0.x, l0.w, l1.z, l2.y};
    float pys[4] = {l0.y, l1.x, l1.w, l2.z};
    float pzs[4] = {l0.z, l1.y, l2.x, l2.w};
    uint kk0[4] = {k00, k10, k20, k30};
    uint kk1[4] = {k01, k11, k21, k31};

    #pragma unroll
    for (int p = 0; p < 4; ++p) {
        float px = pxs[p], py = pys[p], pz = pzs[p];
        float dbest = FLT_MAX; int fbest = 0x7FFFFFFF;
        #pragma unroll
        for (int j = 0; j < 2; ++j) {
            int lf = (int)((j == 0 ? kk0[p] : kk1[p]) & 63u);
            float4 ra = S[lf*6 + 0];
            float4 rb = S[lf*6 + 4];
            float4 rc = S[lf*6 + 5];
            float u, v, w;
            bary_uvw(ra.x, ra.y, ra.z, rb.x, rb.y, rb.z, rc.x, rc.y, rc.z,
                     px, py, pz, u, v, w);
            float d2v;
            {
#pragma clang fp contract(off)
                float cpx = u*ra.x + v*rb.x + w*rc.x;
                float cpy = u*ra.y + v*rb.y + w*rc.y;
                float cpz = u*ra.z + v*rb.z + w*rc.z;
                float dx = cpx - px, dy = cpy - py, dz = cpz - pz;
                d2v = dx*dx + dy*dy + dz*dz;
            }
            int face = cb * FC + lf;
            if (d2v < dbest || (d2v == dbest && face < fbest)) { dbest = d2v; fbest = face; }
        }
        // point-major [b][q][chunk]: finalize reads coalesced uint4
        keys[((size_t)bb * Q_ + q0 + p) * NC + cb] = make_uint2(__float_as_uint(dbest), (uint)fbest);
    }
}

// ---------------------------------------------------------------------------
// Finalize: one WAVE per point; lane l loads chunks 2l,2l+1 exact pairs
// (coalesced uint4), wave lex-(d,face) reduce == jnp.argmin first occurrence
// (true winner is the exact-min of its chunk's top-2 pair, so it is the
// chunk representative). Lane 0 epilogue, contract-off np-order.
__global__ __launch_bounds__(256) void finalize_kernel(
    const float* __restrict__ tri, const float* __restrict__ pts,
    const float* __restrict__ nrm, const float* __restrict__ cmp,
    const int* __restrict__ faces,
    const uint2* __restrict__ keys,
    float* __restrict__ out)
{
#pragma clang fp contract(off)
    const int lane = threadIdx.x & 63;
    const int t = blockIdx.x * 4 + (threadIdx.x >> 6);
    const int bb = t >> 12;            // Q_ = 4096

    uint4 K = ((const uint4*)keys)[(size_t)t * (NC/2) + lane];
    float dbest = __uint_as_float(K.x); int fbest = (int)K.y;
    float d1v   = __uint_as_float(K.z); int f1v   = (int)K.w;
    if (d1v < dbest || (d1v == dbest && f1v < fbest)) { dbest = d1v; fbest = f1v; }
    for (int off = 32; off > 0; off >>= 1) {
        float od = __shfl_down(dbest, off);
        int   of = __shfl_down(fbest, off);
        if (od < dbest || (od == dbest && of < fbest)) { dbest = od; fbest = of; }
    }
    if (lane != 0) return;

    const float* pp = pts + (size_t)t * 3;
    float px = pp[0], py = pp[1], pz = pp[2];

    const int bestf = fbest;
    const float* tg = tri + ((size_t)bb * F_ + bestf) * 9;
    const float* ng = nrm + ((size_t)bb * F_ + bestf) * 9;
    const float* cg = cmp + ((size_t)bb * F_ + bestf) * 9;
    f4u TA = *(const f4u*)(tg), TB = *(const f4u*)(tg + 4);
    float TC = tg[8];
    f4u NA = *(const f4u*)(ng), NB = *(const f4u*)(ng + 4);
    float NCs = ng[8];
    f4u CA = *(const f4u*)(cg), CB = *(const f4u*)(cg + 4);
    float CC = cg[8];

    float u, v, w;
    bary_uvw(TA.x, TA.y, TA.z, TA.w, TB.x, TB.y, TB.z, TB.w, TC,
             px, py, pz, u, v, w);
    u = fminf(fmaxf(u, 0.f), 1.f);
    v = fminf(fmaxf(v, 0.f), 1.f);
    w = fminf(fmaxf(w, 0.f), 1.f);

    float cpx = u * TA.x + v * TA.w + w * TB.z;
    float cpy = u * TA.y + v * TB.x + w * TB.w;
    float cpz = u * TA.z + v * TB.y + w * TC;
    float nx  = u * NA.x + v * NA.w + w * NB.z;
    float ny  = u * NA.y + v * NB.x + w * NB.w;
    float nz  = u * NA.z + v * NB.y + w * NCs;
    float mx  = u * CA.x + v * CA.w + w * CB.z;
    float my  = u * CA.y + v * CB.x + w * CB.w;
    float mz  = u * CA.z + v * CB.y + w * CC;

    const size_t S3 = (size_t)B_ * Q_ * 3;
    out[(size_t)t * 3 + 0] = cpx - px;
    out[(size_t)t * 3 + 1] = cpy - py;
    out[(size_t)t * 3 + 2] = cpz - pz;
    out[S3 + (size_t)t * 3 + 0] = nx;
    out[S3 + (size_t)t * 3 + 1] = ny;
    out[S3 + (size_t)t * 3 + 2] = nz;
    out[2 * S3 + (size_t)t * 3 + 0] = mx;
    out[2 * S3 + (size_t)t * 3 + 1] = my;
    out[2 * S3 + (size_t)t * 3 + 2] = mz;

    int k = 0; float mm = u;
    if (v > mm) { mm = v; k = 1; }
    if (w > mm) { k = 2; }
    out[3 * S3 + t] = (float)faces[((size_t)bb * F_ + bestf) * 3 + k];
}

extern "C" void kernel_launch(void* const* d_in, const int* in_sizes, int n_in,
                              void* d_out, int out_size, void* d_ws, size_t ws_size,
                              hipStream_t stream) {
    const float* tri   = (const float*)d_in[0];
    const float* pts   = (const float*)d_in[1];
    const float* nrm   = (const float*)d_in[2];
    const float* cmp   = (const float*)d_in[3];
    const int*   faces = (const int*)d_in[4];
    float* out = (float*)d_out;

    uint2* keys = (uint2*)d_ws;   // [B][Q][NC] exact (d_bits, face) per chunk

    dim3 g1(Q_ / (PTS * PPT), NC, B_);
    scan_kernel<<<g1, PTS, 0, stream>>>(tri, pts, keys);
    finalize_kernel<<<(B_ * Q_) / 4, 256, 0, stream>>>(
        tri, pts, nrm, cmp, faces, keys, out);
}